// Round 5
// baseline (130.148 us; speedup 1.0000x reference)
//
#include <hip/hip_runtime.h>
#include <stdint.h>

// ---------------------------------------------------------------------------
// NT-Xent loss, B=8 S=512 D=128  ->  N=4096, 2N=8192 rows, K=128.
// loss = mean_i( -pos_i + log(sum_{j!=i} exp(sim_ij)) ),  sim = z_n z_n^T / T
//
// v6: symmetric upper triangle, but blocks own a ROW PANEL with a pipelined
// J-loop.  Block = (I, g): tile-row I, J-tiles Jbase..Jbase+3 (Jbase=I+4g),
// 544 blocks total.  4 waves/block; wave w owns the 64x64 quadrant
// (rowhalf=w>>1, colhalf=w&1) of each 128x128 tile.  A-fragments (16 b128)
// load once per block and persist in registers; B-tiles are register
// DOUBLE-BUFFERED: tile j+1's 16 loads issue before tile j's compute
// (manually unrolled -> compile-time register indices).  This hides the
// L2 latency that kept v2-v5 pinned at ~40 us (all pipes <15% busy, traffic
// models say <=10 us -> exposed-latency bound), and cuts load traffic
// ~270 -> ~170 MB (A reused across 4 tiles).  No LDS, no barriers, no
// atomics in the main loop: per-wave partials go to uncombined scratch
// slabs; ntx_redu sums them (closed-form triangular indexing).
//
//  k1: normalize rows (fp32), pos_half in fp32, store z_n * SCALE as bf16
//      where SCALE^2 = log2(e)/T, so MFMA acc = sim*log2e and
//      exp(sim) == exp2(acc) == one v_exp_f32.
//  k2: symmetric Gram + exp partial sums -> rowpart[544][2][128],
//      colpart[544][4][2][2][64].
//  k3: ntx_redu: panel I: rowsum = row slabs of row-I blocks + col slabs of
//      tiles (I',I), I'<I; lpart[I] = sum log(rowsum).
//  k4: ntx_final: loss = (sum lpart - 2*sum pos_half) / 8192.
// No max-subtraction needed: logits in [-14.3,14.3], sums < 1.3e10 (fp32-safe).
// ---------------------------------------------------------------------------

#define TOTAL   8192
#define NHALF   4096
#define DK      128
#define TEMP_INV 14.285714285714286f
#define SCALE    4.539816f      // sqrt(log2(e)/0.07); SCALE^2 = 20.609929

#define TILE    128
#define TILES   (TOTAL / TILE)            // 64
#define NJ      4                         // J-tiles per block
#define NBLK2   544                       // sum_I ceil((64-I)/4)

typedef short  bf16x8  __attribute__((ext_vector_type(8)));
typedef float  floatx4 __attribute__((ext_vector_type(4)));

#if __has_builtin(__builtin_amdgcn_exp2f)
#define EXP2(x) __builtin_amdgcn_exp2f(x)
#else
#define EXP2(x) exp2f(x)
#endif

__device__ __forceinline__ uint32_t f2bf(float f) {
  uint32_t u = __float_as_uint(f);
  return (u + 0x7fffu + ((u >> 16) & 1u)) >> 16;   // RNE; inputs finite
}
__device__ __forceinline__ uint32_t pack2bf(float lo, float hi) {
  return f2bf(lo) | (f2bf(hi) << 16);
}

// --------------------------- kernel 1: normalize ---------------------------
// grid 1024 x 256. Each wave handles one i (both z_i and z_j rows).
__global__ __launch_bounds__(256) void ntx_norm(
    const float* __restrict__ zi, const float* __restrict__ zj,
    uint32_t* __restrict__ zn,   // packed 2xbf16, [TOTAL][64]
    float* __restrict__ pos)     // [NHALF]
{
  const int t = threadIdx.x;
  const int wave = t >> 6, lane = t & 63;
  const int i = blockIdx.x * 4 + wave;

  const float2 vi = *(const float2*)(zi + (size_t)i * DK + lane * 2);
  const float2 vj = *(const float2*)(zj + (size_t)i * DK + lane * 2);
  float ssi = vi.x * vi.x + vi.y * vi.y;
  float ssj = vj.x * vj.x + vj.y * vj.y;
  float dij = vi.x * vj.x + vi.y * vj.y;
#pragma unroll
  for (int m = 1; m <= 32; m <<= 1) {
    ssi += __shfl_xor(ssi, m, 64);
    ssj += __shfl_xor(ssj, m, 64);
    dij += __shfl_xor(dij, m, 64);
  }
  const float invi = 1.0f / fmaxf(sqrtf(ssi), 1e-12f);
  const float invj = 1.0f / fmaxf(sqrtf(ssj), 1e-12f);

  zn[(size_t)i * 64 + lane] =
      pack2bf(vi.x * invi * SCALE, vi.y * invi * SCALE);
  zn[(size_t)(i + NHALF) * 64 + lane] =
      pack2bf(vj.x * invj * SCALE, vj.y * invj * SCALE);
  if (lane == 0) pos[i] = dij * invi * invj * TEMP_INV;
}

// ---------------- kernel 2: symmetric Gram + exp partial sums --------------
// grid NBLK2 x 256.  Block (I, g): J-tiles Jbase..Jbase+nt-1, Jbase = I+4g.
// Wave w: 64x64 quadrant (rowhalf = w>>1, colhalf = w&1) of each tile.
// Fragment layout (both operands, row-major z):
//   frag[k=q*8+j][m-or-n=c] -> z[base+c][kk*32+q*8 .. +8]
__global__ __launch_bounds__(256, 2) void ntx_gemm(
    const uint16_t* __restrict__ z,   // [TOTAL][DK] bf16 (scaled)
    float* __restrict__ rowpart,      // [NBLK2][2][128]
    float* __restrict__ colpart)      // [NBLK2][NJ][2][2][64]
{
  // decode linear bid -> (I, g);  G(I) = ceil((64-I)/4) = (67-I)>>2
  int b = (int)blockIdx.x, I = 0;
  for (;;) { const int G = (67 - I) >> 2; if (b < G) break; b -= G; ++I; }
  const int Jbase = I + 4 * b;
  const int nt = (TILES - Jbase) < NJ ? (TILES - Jbase) : NJ;

  const int t = threadIdx.x;
  const int w = t >> 6, lane = t & 63;
  const int q = lane >> 4, c = lane & 15;
  const int rhalf = w >> 1, chalf = w & 1;
  const int rowbase = I * TILE + rhalf * 64;

  // A quadrant: 4 strips x 4 k-steps, persistent in registers.
  bf16x8 afrag[4][4];
#pragma unroll
  for (int s = 0; s < 4; ++s) {
    const uint16_t* ap = z + (size_t)(rowbase + s * 16 + c) * DK + q * 8;
#pragma unroll
    for (int kk = 0; kk < 4; ++kk)
      afrag[s][kk] = *(const bf16x8*)(ap + kk * 32);
  }

  float runsum[4][4];
#pragma unroll
  for (int s = 0; s < 4; ++s)
#pragma unroll
    for (int r = 0; r < 4; ++r) runsum[s][r] = 0.0f;

  // B tile loader (16 independent b128 loads) and tile compute.
  auto LOADB = [&](int Jt, bf16x8 (&dst)[4][4]) {
    const int colb = Jt * TILE + chalf * 64;
#pragma unroll
    for (int s = 0; s < 4; ++s) {
      const uint16_t* bp = z + (size_t)(colb + s * 16 + c) * DK + q * 8;
#pragma unroll
      for (int kk = 0; kk < 4; ++kk)
        dst[s][kk] = *(const bf16x8*)(bp + kk * 32);
    }
  };

  auto COMP = [&](int Jt, int jslot, const bf16x8 (&bb)[4][4]) {
    const int colbase = Jt * TILE + chalf * 64;
    const bool isdiag = (Jt == I);         // block/wave-uniform
#pragma unroll
    for (int jt = 0; jt < 4; ++jt) {
      const int jc = colbase + jt * 16;    // col = jc + c
      float colv = 0.0f;
#pragma unroll
      for (int s = 0; s < 4; ++s) {
        floatx4 acc = {0.0f, 0.0f, 0.0f, 0.0f};
#pragma unroll
        for (int kk = 0; kk < 4; ++kk)
          acc = __builtin_amdgcn_mfma_f32_16x16x32_bf16(afrag[s][kk],
                                                        bb[jt][kk], acc,
                                                        0, 0, 0);
        const int rb = rowbase + s * 16;   // row = rb + q*4 + r
        if (isdiag && jc == rb) {          // diagonal 16x16 (wave-uniform)
#pragma unroll
          for (int r = 0; r < 4; ++r) {
            float e = EXP2(acc[r]);
            runsum[s][r] += (q * 4 + r == c) ? 0.0f : e;
          }
        } else {
#pragma unroll
          for (int r = 0; r < 4; ++r) {
            float e = EXP2(acc[r]);
            runsum[s][r] += e;
            colv += e;
          }
        }
      }
      if (!isdiag) {
        // col sums over this wave's 64 rows: combine the 4 q-groups
        colv += __shfl_xor(colv, 16, 64);
        colv += __shfl_xor(colv, 32, 64);
        if (lane < 16) {
          float* cp = colpart +
              ((((size_t)blockIdx.x * NJ + jslot) * 2 + chalf) * 2 + rhalf) * 64;
          cp[jt * 16 + lane] = colv;
        }
      }
    }
  };

  // Software-pipelined J-loop (manually unrolled; nt is block-uniform).
  bf16x8 b0[4][4], b1[4][4];
  LOADB(Jbase, b0);
  if (nt > 1) LOADB(Jbase + 1, b1);      // prefetch tile 1 before compute 0
  COMP(Jbase, 0, b0);
  if (nt > 1) {
    if (nt > 2) LOADB(Jbase + 2, b0);    // prefetch tile 2 (b0 free now)
    COMP(Jbase + 1, 1, b1);
    if (nt > 2) {
      if (nt > 3) LOADB(Jbase + 3, b1);
      COMP(Jbase + 2, 2, b0);
      if (nt > 3) COMP(Jbase + 3, 3, b1);
    }
  }

  // row partials: reduce across the 16 c-lanes (same q), store per wave
#pragma unroll
  for (int s = 0; s < 4; ++s)
#pragma unroll
    for (int r = 0; r < 4; ++r) {
      float v = runsum[s][r];
      v += __shfl_xor(v, 1, 64);
      v += __shfl_xor(v, 2, 64);
      v += __shfl_xor(v, 4, 64);
      v += __shfl_xor(v, 8, 64);
      runsum[s][r] = v;
    }
  if (c == 0) {
    float* rp = rowpart + ((size_t)blockIdx.x * 2 + chalf) * 128 + rhalf * 64;
#pragma unroll
    for (int s = 0; s < 4; ++s)
#pragma unroll
      for (int r = 0; r < 4; ++r)
        rp[s * 16 + q * 4 + r] = runsum[s][r];
  }
}

// ------------------- kernel 3: gather partials, log-reduce -----------------
// grid 64 x 256.  Block I handles global rows [128I, 128I+128).
// rowsum = (row slabs of all blocks in tile-row I) +
//          (col slabs of tiles (I', I) for I' < I).
// Threads 0..127: row gather + log; threads 128..255: col gather.
__global__ __launch_bounds__(256) void ntx_redu(
    const float* __restrict__ rowpart, const float* __restrict__ colpart,
    float* __restrict__ lpart)
{
  __shared__ float sbuf[128];
  __shared__ float red[2];

  const int I = (int)blockIdx.x;
  const int t = (int)threadIdx.x;
  const int o = t & 127;
  const int half = t >> 7;

  float S = 0.0f;
  if (half == 0) {
    int bS = 0;                                   // bidStart(I)
    for (int Ip = 0; Ip < I; ++Ip) bS += (67 - Ip) >> 2;
    const int G = (67 - I) >> 2;
    for (int gg = 0; gg < G; ++gg) {
      const float* rp = rowpart + (size_t)(bS + gg) * 2 * 128;
      S += rp[o] + rp[128 + o];                   // both colhalf slabs
    }
  } else {
    const int h = o >> 6, l = o & 63;
    int bS = 0;
    for (int Ip = 0; Ip < I; ++Ip) {
      const int d = I - Ip;                       // tile (Ip, I)
      const int bid = bS + (d >> 2);
      const int jj = d & 3;
      const float* cp = colpart + (((size_t)bid * NJ + jj) * 2 + h) * 2 * 64;
      S += cp[l] + cp[64 + l];                    // both rowhalf contribs
      bS += (67 - Ip) >> 2;
    }
  }
  if (half) sbuf[o] = S;
  __syncthreads();
  if (!half) {
    float v = __logf(S + sbuf[o]);
#pragma unroll
    for (int m = 1; m <= 32; m <<= 1) v += __shfl_xor(v, m, 64);
    if ((o & 63) == 0) red[o >> 6] = v;
  }
  __syncthreads();
  if (t == 0) lpart[I] = red[0] + red[1];
}

// --------------------------- kernel 4: finalize ----------------------------
__global__ __launch_bounds__(256) void ntx_final(
    const float* __restrict__ lpart, const float* __restrict__ pos,
    float* __restrict__ out)
{
  const int t = threadIdx.x;
  float acc = (t < TILES) ? lpart[t] : 0.0f;
  for (int r = t; r < NHALF; r += 256) acc -= 2.0f * pos[r];
#pragma unroll
  for (int m = 1; m <= 32; m <<= 1) acc += __shfl_xor(acc, m, 64);
  __shared__ float red[4];
  if ((t & 63) == 0) red[t >> 6] = acc;
  __syncthreads();
  if (t == 0) out[0] = (red[0] + red[1] + red[2] + red[3]) / (float)TOTAL;
}

// ---------------------------------------------------------------------------
extern "C" void kernel_launch(void* const* d_in, const int* in_sizes, int n_in,
                              void* d_out, int out_size, void* d_ws,
                              size_t ws_size, hipStream_t stream) {
  const float* zi = (const float*)d_in[0];
  const float* zj = (const float*)d_in[1];
  float* out = (float*)d_out;

  char* ws = (char*)d_ws;
  uint16_t* zn = (uint16_t*)ws;                              // 2 MiB bf16
  size_t off = (size_t)TOTAL * DK * 2;
  float* rowpart = (float*)(ws + off);                       // 557 KB
  off += (size_t)NBLK2 * 2 * 128 * 4;
  float* colpart = (float*)(ws + off);                       // 2.23 MB
  off += (size_t)NBLK2 * NJ * 2 * 2 * 64 * 4;
  float* lpart = (float*)(ws + off);                         // 256 B
  off += 256 * 4;
  float* pos = (float*)(ws + off);                           // 16 KB

  ntx_norm<<<dim3(NHALF / 4), dim3(256), 0, stream>>>(zi, zj, (uint32_t*)zn,
                                                      pos);
  ntx_gemm<<<dim3(NBLK2), dim3(256), 0, stream>>>(zn, rowpart, colpart);
  ntx_redu<<<dim3(TILES), dim3(256), 0, stream>>>(rowpart, colpart, lpart);
  ntx_final<<<dim3(1), dim3(256), 0, stream>>>(lpart, pos, out);
}

// Round 6
// 90.411 us; speedup vs baseline: 1.4395x; 1.4395x over previous
//
#include <hip/hip_runtime.h>
#include <stdint.h>

// ---------------------------------------------------------------------------
// NT-Xent loss, B=8 S=512 D=128  ->  N=4096, 2N=8192 rows, K=128.
// loss = mean_i( -pos_i + log(sum_{j!=i} exp(sim_ij)) ),  sim = z_n z_n^T / T
//
// v7: symmetric upper-triangle 128x128 tiles (2080 blocks), now 512 threads
// (8 waves) per block, __launch_bounds__(512,8) pinning VGPR<=64 so 8
// waves/SIMD (32 waves/CU) are resident -- v2..v6 never exceeded ~3/SIMD
// and were latency-bound at 10-15% duty cycle (all pipes <15% busy at
// 37-53us while every throughput model says <=10us).  Structure:
//   * stage the whole 128-col B panel to LDS ONCE per block (coalesced,
//     +16B/row pad -> conflict-free, verified 0 LDS conflicts in v4),
//   * ONE barrier, then each wave computes 16 rows x 128 cols from
//     registers + LDS with no further synchronization,
//   * col partials combined via 4KB LDS at the epilogue; no atomics.
// Per-wave regs: afrag 16 + bfrag 16 + acc/runsum 8 + misc ~= 56 < 64.
// LDS 34.8KB + 4KB -> 4 blocks/CU = 2048 thr/CU (the hardware cap).
//
//  k1: normalize rows (fp32), pos_half in fp32, store z_n * SCALE as bf16
//      where SCALE^2 = log2(e)/T, so MFMA acc = sim*log2e and
//      exp(sim) == exp2(acc) == one v_exp_f32.
//  k2: symmetric Gram + exp row/col partial sums -> scratch[blk][256].
//  k3: ntx_redu: rowsum_i = sum of 64 block partials (triangular indexing).
//  k4: ntx_final: loss = (sum lpart - 2*sum pos_half) / 8192.
// No max-subtraction needed: logits in [-14.3,14.3], sums < 1.3e10 (fp32-safe).
// ---------------------------------------------------------------------------

#define TOTAL   8192
#define NHALF   4096
#define DK      128
#define TEMP_INV 14.285714285714286f
#define SCALE    4.539816f      // sqrt(log2(e)/0.07); SCALE^2 = 20.609929

#define TILE    128                       // square tile edge
#define TILES   (TOTAL / TILE)            // 64
#define NBLK    (TILES * (TILES + 1) / 2) // 2080 super-diagonal tiles
#define WAVES   8

typedef short  bf16x8  __attribute__((ext_vector_type(8)));
typedef float  floatx4 __attribute__((ext_vector_type(4)));

#if __has_builtin(__builtin_amdgcn_exp2f)
#define EXP2(x) __builtin_amdgcn_exp2f(x)
#else
#define EXP2(x) exp2f(x)
#endif

__device__ __forceinline__ uint32_t f2bf(float f) {
  uint32_t u = __float_as_uint(f);
  return (u + 0x7fffu + ((u >> 16) & 1u)) >> 16;   // RNE; inputs finite
}
__device__ __forceinline__ uint32_t pack2bf(float lo, float hi) {
  return f2bf(lo) | (f2bf(hi) << 16);
}

// --------------------------- kernel 1: normalize ---------------------------
// grid 1024 x 256. Each wave handles one i (both z_i and z_j rows).
__global__ __launch_bounds__(256) void ntx_norm(
    const float* __restrict__ zi, const float* __restrict__ zj,
    uint32_t* __restrict__ zn,   // packed 2xbf16, [TOTAL][64]
    float* __restrict__ pos)     // [NHALF]
{
  const int t = threadIdx.x;
  const int wave = t >> 6, lane = t & 63;
  const int i = blockIdx.x * 4 + wave;

  const float2 vi = *(const float2*)(zi + (size_t)i * DK + lane * 2);
  const float2 vj = *(const float2*)(zj + (size_t)i * DK + lane * 2);
  float ssi = vi.x * vi.x + vi.y * vi.y;
  float ssj = vj.x * vj.x + vj.y * vj.y;
  float dij = vi.x * vj.x + vi.y * vj.y;
#pragma unroll
  for (int m = 1; m <= 32; m <<= 1) {
    ssi += __shfl_xor(ssi, m, 64);
    ssj += __shfl_xor(ssj, m, 64);
    dij += __shfl_xor(dij, m, 64);
  }
  const float invi = 1.0f / fmaxf(sqrtf(ssi), 1e-12f);
  const float invj = 1.0f / fmaxf(sqrtf(ssj), 1e-12f);

  zn[(size_t)i * 64 + lane] =
      pack2bf(vi.x * invi * SCALE, vi.y * invi * SCALE);
  zn[(size_t)(i + NHALF) * 64 + lane] =
      pack2bf(vj.x * invj * SCALE, vj.y * invj * SCALE);
  if (lane == 0) pos[i] = dij * invi * invj * TEMP_INV;
}

// ---------------- kernel 2: symmetric Gram + exp partial sums --------------
// grid NBLK x 512. Linear block id -> upper-triangular tile (I, J), J >= I.
// Wave w owns rows [i0+16w, i0+16w+16) x all 128 cols.
// Fragment layout (verified): frag[k=q*8+kk*32+j][m-or-n=c]
//   A -> z[rowbase+c][kk*32+q*8 ..+8] ; B -> lds row (jt*16+c), 16B (kk*4+q)
__global__ __launch_bounds__(512, 8) void ntx_gemm(
    const uint16_t* __restrict__ z,   // [TOTAL][DK] bf16 (scaled)
    float* __restrict__ scratch)      // [NBLK][256]: 128 row + 128 col parts
{
  __shared__ uint4 lb4[TILE * 17];    // 128 rows x (256B data + 16B pad)
  __shared__ float colacc[WAVES][TILE];

  // map linear block id -> (I, J) with J >= I  (row-major upper triangle)
  int I = 0, rem = (int)blockIdx.x, span = TILES;
  while (rem >= span) { rem -= span; --span; ++I; }
  const int J = I + rem;
  const bool isdiag = (I == J);

  const int t = threadIdx.x;
  const int w = t >> 6, lane = t & 63;
  const int q = lane >> 4, c = lane & 15;
  const int i0 = I * TILE;
  const int j0 = J * TILE;
  const int rowbase = i0 + w * 16;

  // A fragment: this wave's 16 rows, 4 k-steps (issue before staging so the
  // scattered-load latency hides under the stage + barrier).
  bf16x8 afrag[4];
  {
    const uint16_t* ap = z + (size_t)(rowbase + c) * DK + q * 8;
#pragma unroll
    for (int kk = 0; kk < 4; ++kk)
      afrag[kk] = *(const bf16x8*)(ap + kk * 32);
  }

  // stage the full B panel (rows j0..j0+127 of z), coalesced 16B/thread.
  {
    const int r0 = t >> 4, ch = t & 15;
#pragma unroll
    for (int p = 0; p < 4; ++p) {
      const int r = r0 + p * 32;
      lb4[r * 17 + ch] = *(const uint4*)(z + (size_t)(j0 + r) * DK + ch * 8);
    }
  }
  __syncthreads();

  float runsum[4] = {0.0f, 0.0f, 0.0f, 0.0f};

#pragma unroll
  for (int jt = 0; jt < TILE / 16; ++jt) {
    const int jc = j0 + jt * 16;       // col = jc + c
    bf16x8 bfrag[4];
#pragma unroll
    for (int kk = 0; kk < 4; ++kk)
      bfrag[kk] = *(const bf16x8*)&lb4[(jt * 16 + c) * 17 + kk * 4 + q];

    floatx4 acc = {0.0f, 0.0f, 0.0f, 0.0f};
#pragma unroll
    for (int kk = 0; kk < 4; ++kk)
      acc = __builtin_amdgcn_mfma_f32_16x16x32_bf16(afrag[kk], bfrag[kk],
                                                    acc, 0, 0, 0);
    // row = rowbase + q*4 + r
    if (isdiag && jc == rowbase) {       // diagonal 16x16 (wave-uniform)
#pragma unroll
      for (int r = 0; r < 4; ++r) {
        float e = EXP2(acc[r]);
        runsum[r] += (q * 4 + r == c) ? 0.0f : e;
      }
    } else {
      float colv = 0.0f;
#pragma unroll
      for (int r = 0; r < 4; ++r) {
        float e = EXP2(acc[r]);
        runsum[r] += e;
        colv += e;
      }
      if (!isdiag) {
        // col sums over this wave's 16 rows: combine the 4 q-groups
        colv += __shfl_xor(colv, 16, 64);
        colv += __shfl_xor(colv, 32, 64);
        if (lane < 16) colacc[w][jt * 16 + lane] = colv;
      }
    }
  }

  // row partials: reduce across the 16 c-lanes (same q), store per block
  float* sblk = scratch + (size_t)blockIdx.x * 256;
#pragma unroll
  for (int r = 0; r < 4; ++r) {
    float v = runsum[r];
    v += __shfl_xor(v, 1, 64);
    v += __shfl_xor(v, 2, 64);
    v += __shfl_xor(v, 4, 64);
    v += __shfl_xor(v, 8, 64);
    if (c == 0) sblk[w * 16 + q * 4 + r] = v;
  }

  // column partials: combine the 8 waves (off-diagonal blocks only)
  __syncthreads();
  if (!isdiag && t < TILE) {
    float s = 0.0f;
#pragma unroll
    for (int ww = 0; ww < WAVES; ++ww) s += colacc[ww][t];
    sblk[128 + t] = s;
  }
}

// ------------------- kernel 3: gather partials, log-reduce -----------------
// grid 64 x 256. Block I handles rows [128I, 128I+128).
// rowsum_i = sum_{J=I..63} scratch[id(I,J)][o] + sum_{I'<I} scratch[id(I',I)][128+o]
// id(I,J) = I*64 - I(I-1)/2 + (J-I);  id(I'+1,I) - id(I',I) = 63 - I'.
// Threads 0..127 gather the row-partial loop, 128..255 the col-partial loop.
__global__ __launch_bounds__(256) void ntx_redu(
    const float* __restrict__ scratch, float* __restrict__ lpart)
{
  __shared__ float sbuf[128];
  __shared__ float red[2];

  const int I = (int)blockIdx.x;
  const int o = (int)threadIdx.x & 127;
  const int half = (int)threadIdx.x >> 7;

  float S = 0.0f;
  if (half == 0) {
    int id = I * TILES - (I * (I - 1)) / 2;      // id(I, I)
#pragma unroll 8
    for (int Jt = I; Jt < TILES; ++Jt, ++id)
      S += scratch[(size_t)id * 256 + o];
  } else {
    int idc = I;                                  // id(0, I)
#pragma unroll 8
    for (int Ip = 0; Ip < I; ++Ip) {
      S += scratch[(size_t)idc * 256 + 128 + o];
      idc += TILES - 1 - Ip;
    }
  }
  if (half) sbuf[o] = S;
  __syncthreads();
  if (!half) {
    float v = __logf(S + sbuf[o]);
#pragma unroll
    for (int m = 1; m <= 32; m <<= 1) v += __shfl_xor(v, m, 64);
    if ((o & 63) == 0) red[o >> 6] = v;
  }
  __syncthreads();
  if (threadIdx.x == 0) lpart[I] = red[0] + red[1];
}

// --------------------------- kernel 4: finalize ----------------------------
__global__ __launch_bounds__(256) void ntx_final(
    const float* __restrict__ lpart, const float* __restrict__ pos,
    float* __restrict__ out)
{
  const int t = threadIdx.x;
  float acc = (t < TILES) ? lpart[t] : 0.0f;
  for (int r = t; r < NHALF; r += 256) acc -= 2.0f * pos[r];
#pragma unroll
  for (int m = 1; m <= 32; m <<= 1) acc += __shfl_xor(acc, m, 64);
  __shared__ float red[4];
  if ((t & 63) == 0) red[t >> 6] = acc;
  __syncthreads();
  if (t == 0) out[0] = (red[0] + red[1] + red[2] + red[3]) / (float)TOTAL;
}

// ---------------------------------------------------------------------------
extern "C" void kernel_launch(void* const* d_in, const int* in_sizes, int n_in,
                              void* d_out, int out_size, void* d_ws,
                              size_t ws_size, hipStream_t stream) {
  const float* zi = (const float*)d_in[0];
  const float* zj = (const float*)d_in[1];
  float* out = (float*)d_out;

  char* ws = (char*)d_ws;
  uint16_t* zn      = (uint16_t*)ws;                          // 2 MiB bf16
  float*    scratch = (float*)(ws + (size_t)TOTAL * DK * 2);  // 2.13 MB
  float*    lpart   = (float*)(ws + (size_t)TOTAL * DK * 2
                               + (size_t)NBLK * 256 * 4);     // 256 B
  float*    pos     = (float*)(ws + (size_t)TOTAL * DK * 2
                               + (size_t)NBLK * 256 * 4 + 256);  // 16 KB

  ntx_norm<<<dim3(NHALF / 4), dim3(256), 0, stream>>>(zi, zj, (uint32_t*)zn,
                                                      pos);
  ntx_gemm<<<dim3(NBLK), dim3(512), 0, stream>>>(zn, scratch);
  ntx_redu<<<dim3(TILES), dim3(256), 0, stream>>>(scratch, lpart);
  ntx_final<<<dim3(1), dim3(256), 0, stream>>>(lpart, pos, out);
}